// Round 1
// 75.633 us; speedup vs baseline: 1.0756x; 1.0756x over previous
//
#include <hip/hip_runtime.h>
#include <math.h>

#define N 512
#define D 512
#define NC 10
#define EPSF 1e-8f

typedef __attribute__((ext_vector_type(8))) __bf16 bf16x8;
typedef __attribute__((ext_vector_type(4))) float f32x4;

__device__ __forceinline__ unsigned short f2bf_rne(float f) {
  unsigned u = __float_as_uint(f);
  u += 0x7fffu + ((u >> 16) & 1u);
  return (unsigned short)(u >> 16);
}
__device__ __forceinline__ float bf2f(unsigned short h) {
  return __uint_as_float(((unsigned)h) << 16);
}

// ---------------- Kernel 0: fp32 -> bf16 hi/lo split (+ class_pos, out=0) ----
__global__ __launch_bounds__(256) void k_convert(
    const float* __restrict__ pred, const float* __restrict__ dist_raw,
    unsigned short* __restrict__ XH, unsigned short* __restrict__ XL,
    float* __restrict__ class_pos, float* __restrict__ out) {
  const int idx = blockIdx.x * 256 + threadIdx.x;  // 65536 threads x 4 floats
  float4 v = ((const float4*)pred)[idx];
  ushort4 h, l;
  h.x = f2bf_rne(v.x); l.x = f2bf_rne(v.x - bf2f(h.x));
  h.y = f2bf_rne(v.y); l.y = f2bf_rne(v.y - bf2f(h.y));
  h.z = f2bf_rne(v.z); l.z = f2bf_rne(v.z - bf2f(h.z));
  h.w = f2bf_rne(v.w); l.w = f2bf_rne(v.w - bf2f(h.w));
  ((ushort4*)XH)[idx] = h;
  ((ushort4*)XL)[idx] = l;
  if (idx == 0) {
    out[0] = 0.0f;  // d_out is poisoned each launch; k_rows accumulates
    float acc = 0.0f;
    class_pos[0] = 0.0f;
    for (int c = 0; c < NC - 1; ++c) {
      acc += log1pf(expf(dist_raw[c]));
      class_pos[c + 1] = acc;
    }
  }
}

// ---------------- Kernel 1: Gram via bf16 split MFMA ------------------------
// grid (16,16), block 256 (4 waves). 32x32 tile/block, each wave one 16x16
// quadrant. G = hi*hi^T + hi*lo^T + lo*hi^T + lo*lo^T (4 independent accs).
// LDS: 4 arrays [32 rows][256 k] bf16, 16B-granule XOR swizzle g^=(row&7):
// linear global_load_lds dest + inverse-swizzled per-lane SOURCE address,
// swizzled ds_read (T21 both-sides rule). K chunked 2x256 (64 KiB LDS).
__global__ __launch_bounds__(256) void k_gram(
    const unsigned short* __restrict__ XH, const unsigned short* __restrict__ XL,
    float* __restrict__ G, float* __restrict__ inv_n) {
  __shared__ unsigned short LB[4][32][256];  // 64 KiB

  const int t = threadIdx.x;
  const int lane = t & 63;
  const int wid = t >> 6;  // 0..3
  const int bi = blockIdx.y, bj = blockIdx.x;

  // staging: wave wid owns array wid: 0=A_hi 1=A_lo 2=B_hi 3=B_lo
  const unsigned short* __restrict__ srcArr = (wid & 1) ? XL : XH;
  const int tileBase = ((wid < 2) ? bi : bj) * 32;

  // MFMA fragment addressing: A[m=lane&15][k=8*(lane>>4)+b], B[k][n=lane&15]
  const int frow = lane & 15;
  const int kg = lane >> 4;  // 0..3
  const int wr = wid >> 1, wc = wid & 1;
  const int arow = wr * 16 + frow;
  const int brow = wc * 16 + frow;

  f32x4 ahh = {0.f, 0.f, 0.f, 0.f};
  f32x4 ahl = ahh, alh = ahh, all_ = ahh;

  for (int c = 0; c < 2; ++c) {  // two K-chunks of 256
#pragma unroll
    for (int i = 0; i < 16; ++i) {
      const int gr = i * 64 + lane;              // granule index within array
      const int row = gr >> 5;                   // 0..31
      const int gsw = (lane & 31) ^ (row & 7);   // inverse-swizzled src granule
      const unsigned short* src =
          srcArr + (size_t)(tileBase + row) * D + c * 256 + gsw * 8;
      unsigned short* dst = &LB[wid][0][0] + (size_t)i * 64 * 8;  // wave-uniform
      __builtin_amdgcn_global_load_lds(
          (const __attribute__((address_space(1))) void*)src,
          (__attribute__((address_space(3))) void*)dst, 16, 0, 0);
    }
    __syncthreads();  // vmcnt(0) drain + barrier
#pragma unroll
    for (int kc = 0; kc < 8; ++kc) {
      const int ga = (((kc * 4 + kg) ^ (arow & 7))) * 8;
      const int gb = (((kc * 4 + kg) ^ (brow & 7))) * 8;
      bf16x8 ah = *(const bf16x8*)&LB[0][arow][ga];
      bf16x8 al = *(const bf16x8*)&LB[1][arow][ga];
      bf16x8 bh = *(const bf16x8*)&LB[2][brow][gb];
      bf16x8 bl = *(const bf16x8*)&LB[3][brow][gb];
      ahh = __builtin_amdgcn_mfma_f32_16x16x32_bf16(ah, bh, ahh, 0, 0, 0);
      ahl = __builtin_amdgcn_mfma_f32_16x16x32_bf16(ah, bl, ahl, 0, 0, 0);
      alh = __builtin_amdgcn_mfma_f32_16x16x32_bf16(al, bh, alh, 0, 0, 0);
      all_ = __builtin_amdgcn_mfma_f32_16x16x32_bf16(al, bl, all_, 0, 0, 0);
    }
    __syncthreads();  // all reads done before next chunk overwrites
  }

  // C/D: col = lane&15, row = (lane>>4)*4 + r   [m89-verified]
  const int gcol = bj * 32 + wc * 16 + frow;
  const int grow0 = bi * 32 + wr * 16 + kg * 4;
#pragma unroll
  for (int r = 0; r < 4; ++r) {
    const float v = ahh[r] + all_[r] + (ahl[r] + alh[r]);
    G[(size_t)(grow0 + r) * N + gcol] = v;
    if (bi == bj && (grow0 + r) == gcol)
      inv_n[gcol] = 1.0f / fmaxf(sqrtf(v), EPSF);
  }
}

// ---------------- Kernel 2: per-row loss + global mean ----------------------
// Negatives stay in registers (masked -1e30); only ~N/NC positives compacted.
__global__ __launch_bounds__(256) void k_rows(
    const float* __restrict__ G, const int* __restrict__ target,
    const float* __restrict__ inv_n, const float* __restrict__ class_pos,
    float* __restrict__ out) {
  const int i = blockIdx.x;
  const int tid = threadIdx.x;

  __shared__ float s_p[N];
  __shared__ float s_cp[16];
  __shared__ int s_np;
  __shared__ float s_part[4];

  if (tid == 0) s_np = 0;
  if (tid < NC) s_cp[tid] = class_pos[tid];
  __syncthreads();

  const int ti = target[i];
  const float inv_i = inv_n[i];
  const float cpi = s_cp[ti];

  float a0, a1;
  {
    const int j = tid;
    const float cosv = G[(size_t)i * N + j] * inv_i * inv_n[j];
    const int tj = target[j];
    if (tj != ti) {
      a0 = cosv + fabsf(cpi - s_cp[tj]);
    } else {
      a0 = -1e30f;
      if (j != i) { int k = atomicAdd(&s_np, 1); s_p[k] = cosv; }
    }
  }
  {
    const int j = tid + 256;
    const float cosv = G[(size_t)i * N + j] * inv_i * inv_n[j];
    const int tj = target[j];
    if (tj != ti) {
      a1 = cosv + fabsf(cpi - s_cp[tj]);
    } else {
      a1 = -1e30f;
      if (j != i) { int k = atomicAdd(&s_np, 1); s_p[k] = cosv; }
    }
  }
  __syncthreads();

  const int np = s_np;
  const int nn = N - 1 - np;  // negatives = N - (class size)
  float acc = 0.0f;
  for (int kk = 0; kk < np; ++kk) {
    const float ck = s_p[kk];  // LDS broadcast
    acc += fmaxf(a0 - ck, 0.0f) + fmaxf(a1 - ck, 0.0f);
  }

#pragma unroll
  for (int off = 32; off > 0; off >>= 1) acc += __shfl_down(acc, off);
  if ((tid & 63) == 0) s_part[tid >> 6] = acc;
  __syncthreads();
  if (tid == 0) {
    const float total = s_part[0] + s_part[1] + s_part[2] + s_part[3];
    if (np > 0 && nn > 0) {
      atomicAdd(out, total / ((float)nn * (float)nn * (float)np) / (float)N);
    }
  }
}

extern "C" void kernel_launch(void* const* d_in, const int* in_sizes, int n_in,
                              void* d_out, int out_size, void* d_ws, size_t ws_size,
                              hipStream_t stream) {
  const float* pred = (const float*)d_in[0];
  const float* dist_raw = (const float*)d_in[1];
  const int* target = (const int*)d_in[2];
  float* out = (float*)d_out;

  float* G = (float*)d_ws;                    // 1 MiB
  float* inv_n = G + (size_t)N * N;           // 2 KiB
  float* class_pos = inv_n + N;               // 64 B
  unsigned short* XH = (unsigned short*)(class_pos + 16);  // 512 KiB (16B-aligned)
  unsigned short* XL = XH + (size_t)N * D;                 // 512 KiB

  k_convert<<<256, 256, 0, stream>>>(pred, dist_raw, XH, XL, class_pos, out);
  k_gram<<<dim3(16, 16), 256, 0, stream>>>(XH, XL, G, inv_n);
  k_rows<<<N, 256, 0, stream>>>(G, target, inv_n, class_pos, out);
}